// Round 16
// baseline (37.248 us; speedup 1.0000x reference)
//
#include <hip/hip_runtime.h>
#include <math.h>

#define SRATE   24000.0
#define NB      8
#define NT      48000
#define NH      60
#define NC      100
#define NFMT    5
#define CTS     64
#define NCH     (NT / CTS)       // 750 chunks per batch (= 1 wave each)
#define TWO_PI  6.283185307179586476925286766559
#define PSC     (1.0f / 1024.0f) // exact 2^-10 prescale
#define NYQS    11.71875f        // 12000 * 2^-10

typedef float v2f __attribute__((ext_vector_type(2)));

// ---------------- kernel 1: per-chunk f0 sums (double) ----------------
__global__ __launch_bounds__(256) void k_partial(const float* __restrict__ f0,
                                                 double* __restrict__ part) {
    int b = blockIdx.y;
    int ch = blockIdx.x * 4 + (threadIdx.x >> 6);
    int lane = threadIdx.x & 63;
    if (ch < NCH) {
        int t = ch * CTS + lane;
        double q = (double)f0[b * NT + t];
        #pragma unroll
        for (int off = 32; off > 0; off >>= 1)
            q += __shfl_down(q, off, 64);
        if (lane == 0) part[b * NCH + ch] = q;
    }
}

// ---------------- kernel 2: main synthesis ----------------
// 64-thread blocks = 1 wave = 1 chunk. The wave's amp data (64 ts x 240B =
// 15360B, CONTIGUOUS in memory) is staged to LDS via 15 global_load_lds
// width-16 instructions -- each a perfectly coalesced 1KB linear block
// (vs ~17-line divergent VMEM before). Preamble loads issue first, staging
// second; preamble compute overlaps staging flight; one vmcnt(0) before
// the 4 compute passes, which read amps via ds_read_b128.
__global__ __launch_bounds__(64) void k_main(const float* __restrict__ f0,
                                             const float* __restrict__ amps,
                                             const float* __restrict__ ffq,
                                             const float* __restrict__ fbw,
                                             const float* __restrict__ fam,
                                             const float* __restrict__ initp,
                                             const double* __restrict__ part,
                                             float* __restrict__ out) {
    int b = blockIdx.y;
    int ch = blockIdx.x;               // 750 blocks/batch, one wave each
    int lane = threadIdx.x;            // 0..63
    int t0 = ch * CTS;
    int g0 = lane >> 2, j = lane & 3;

    __shared__ float smem[CTS * 60];   // 64 rows x 240B = 15360B, linear

    // ---- preamble loads issue FIRST (so waits on them don't drain staging) --
    const double* pb = part + b * NCH;
    double pv[12];
    #pragma unroll
    for (int k = 0; k < 12; ++k) {
        int idx = k * 64 + lane;
        pv[k] = (idx < NCH) ? pb[idx] : 0.0;
    }
    float f0v = f0[b * NT + t0 + lane];

    double srcd = (double)(t0 + lane) * (99.0 / 47999.0);
    int i0 = (int)srcd;
    if (i0 > NC - 2) i0 = NC - 2;
    float frac = (float)(srcd - (double)i0);
    float omf = 1.0f - frac;
    const float* Fq = ffq + (b * NC + i0) * NFMT;
    const float* Bw = fbw + (b * NC + i0) * NFMT;
    const float* Am = fam + (b * NC + i0) * NFMT;
    float tq[10];
    #pragma unroll
    for (int f = 0; f < NFMT; ++f) { tq[f] = Fq[f]; tq[5 + f] = Fq[NFMT + f]; }
    float tb[10];
    #pragma unroll
    for (int f = 0; f < NFMT; ++f) { tb[f] = Bw[f]; tb[5 + f] = Bw[NFMT + f]; }
    float ta[10];
    #pragma unroll
    for (int f = 0; f < NFMT; ++f) { ta[f] = Am[f]; ta[5 + f] = Am[NFMT + f]; }

    // ---- staging: 15 x 1KB perfectly-linear global->LDS ----
    const float* gsrc = amps + (size_t)b * NT * NH + (size_t)t0 * NH;
    #pragma unroll
    for (int i = 0; i < 15; ++i) {
        __builtin_amdgcn_global_load_lds(
            (const __attribute__((address_space(1))) void*)(gsrc + i * 256 + lane * 4),
            (__attribute__((address_space(3))) void*)(&smem[i * 256]),
            16, 0, 0);
    }

    // ---- preamble compute (staging in flight) ----
    double sl = 0.0, sa = 0.0;
    #pragma unroll
    for (int k = 0; k < 12; ++k) {
        int idx = k * 64 + lane;
        sa += pv[k];
        if (idx < ch) sl += pv[k];
    }
    #pragma unroll
    for (int off = 1; off < 64; off <<= 1) {
        sl += __shfl_xor(sl, off, 64);
        sa += __shfl_xor(sa, off, 64);
    }
    double initrev = (double)initp[b] * (1.0 / TWO_PI);
    if (ch == 0 && lane == 0) {        // designated wave: final phase
        double rv = sa * (1.0 / SRATE) + initrev;
        out[NB * NT + b] = (float)((rv - floor(rv)) * TWO_PI);
    }

    double pfrac = sl * (1.0 / SRATE) + initrev;
    float prefF = (float)(pfrac - floor(pfrac));   // [0,1), wave-uniform

    float incf = f0v;
    #pragma unroll
    for (int off = 1; off < 64; off <<= 1) {
        float n = __shfl_up(incf, off, 64);
        if (lane >= off) incf += n;
    }
    float rev_l = __builtin_amdgcn_fractf(prefF + incf * (1.0f / 24000.0f));
    float f0s_l = f0v * PSC;

    float fqs[NFMT], c1s[NFMT], c2s[NFMT];
    #pragma unroll
    for (int f = 0; f < NFMT; ++f) {
        float fqv = tq[f] * omf + tq[5 + f] * frac;
        float bwv = tb[f] * omf + tb[5 + f] * frac;
        float amv = ta[f] * omf + ta[5 + f] * frac;
        float bws = bwv * PSC;
        fqs[f] = fqv * PSC;
        c2s[f] = bws * bws;
        c1s[f] = amv * c2s[f];
    }

    // ---- all staging complete before LDS reads ----
    asm volatile("s_waitcnt vmcnt(0)" ::: "memory");
    __builtin_amdgcn_sched_barrier(0);

    // ---- one pass = 16 ts x 4 lanes; lane j: quads {4j+1..4} +0/16/32/48 ----
    auto do_pass = [&](int p) {
        int gp = (p << 4) + g0;
        float f0s   = __shfl(f0s_l, gp, 64);
        float rev_g = __shfl(rev_l, gp, 64);
        float fq[NFMT], c1[NFMT], c2[NFMT];
        #pragma unroll
        for (int f = 0; f < NFMT; ++f) {
            fq[f] = __shfl(fqs[f], gp, 64);
            c1[f] = __shfl(c1s[f], gp, 64);
            c2[f] = __shfl(c2s[f], gp, 64);
        }
        const float4* rowp = (const float4*)&smem[gp * 60];  // 240B row
        float4 q0 = rowp[j];
        float4 q1 = rowp[4 + j];
        float4 q2 = rowp[8 + j];
        float4 q3 = (j < 3) ? rowp[12 + j]
                            : make_float4(0.f, 0.f, 0.f, 0.f);
        float hb = (float)(j << 2);
        auto sd = [&](float k) {
            return __builtin_amdgcn_sinf(
                __builtin_amdgcn_fractf((hb + k) * rev_g));
        };
        v2f s01 = {sd(1.0f),  sd(2.0f)};
        v2f s23 = {sd(3.0f),  sd(4.0f)};
        v2f s45 = {sd(17.0f), sd(18.0f)};
        v2f s67 = {sd(19.0f), sd(20.0f)};
        float c16 = __builtin_amdgcn_cosf(
            __builtin_amdgcn_fractf(16.0f * rev_g));    // cos(16*theta)
        v2f cv = {2.0f * c16, 2.0f * c16};
        v2f s89 = cv * s45 - s01;                       // (hb+33,34)
        v2f sAB = cv * s67 - s23;                       // (hb+35,36)
        v2f sCD = cv * s89 - s45;                       // (hb+49,50)
        v2f sEF = cv * sAB - s67;                       // (hb+51,52)
        v2f acc2 = {0.0f, 0.0f};
        auto pairf = [&](float h1, v2f sn, float a0, float a1) {
            v2f hfl = {h1, h1 + 1.0f};
            v2f hs = f0s * hfl;                         // f0*h * 2^-10
            v2f pN = {1.0f, 1.0f}, pD = {1.0f, 1.0f};
            #pragma unroll
            for (int f = 0; f < NFMT; ++f) {
                v2f d = hs - fq[f];
                v2f e = d * d + c2[f];
                pN *= e + c1[f];
                pD *= e;
            }
            float R = __builtin_amdgcn_rcpf(pD.x * pD.y);
            v2f fac = {pN.x * pD.y * R, pN.y * pD.x * R};
            v2f fm;
            fm.x = (hs.x < NYQS) ? fac.x : 0.0f;        // nyquist mask
            fm.y = (hs.y < NYQS) ? fac.y : 0.0f;
            v2f aa = {a0, a1};
            acc2 += (sn * aa) * fm;
        };
        pairf(hb + 1.0f,  s01, q0.x, q0.y);
        pairf(hb + 3.0f,  s23, q0.z, q0.w);
        pairf(hb + 17.0f, s45, q1.x, q1.y);
        pairf(hb + 19.0f, s67, q1.z, q1.w);
        pairf(hb + 33.0f, s89, q2.x, q2.y);
        pairf(hb + 35.0f, sAB, q2.z, q2.w);
        pairf(hb + 49.0f, sCD, q3.x, q3.y);
        pairf(hb + 51.0f, sEF, q3.z, q3.w);
        float acc = acc2.x + acc2.y;
        acc += __shfl_xor(acc, 1, 64);
        acc += __shfl_xor(acc, 2, 64);
        if (j == 0) {
            if (!(f0s > 0.0f)) acc = 0.0f;              // voiced mask
            out[b * NT + t0 + (p << 4) + g0] = acc;
        }
    };

    do_pass(0);
    do_pass(1);
    do_pass(2);
    do_pass(3);
}

extern "C" void kernel_launch(void* const* d_in, const int* in_sizes, int n_in,
                              void* d_out, int out_size, void* d_ws, size_t ws_size,
                              hipStream_t stream) {
    const float* f0    = (const float*)d_in[0];
    const float* amps  = (const float*)d_in[1];
    const float* ffq   = (const float*)d_in[2];
    const float* fbw   = (const float*)d_in[3];
    const float* fam   = (const float*)d_in[4];
    const float* initp = (const float*)d_in[5];
    float* out = (float*)d_out;

    double* part = (double*)d_ws;                    // NB*NCH doubles (48 KB)

    dim3 gpart((NCH + 3) / 4, NB);
    k_partial<<<gpart, 256, 0, stream>>>(f0, part);
    dim3 gmain(NCH, NB);
    k_main<<<gmain, 64, 0, stream>>>(f0, amps, ffq, fbw, fam, initp, part, out);
}

// Round 17
// 34.826 us; speedup vs baseline: 1.0695x; 1.0695x over previous
//
#include <hip/hip_runtime.h>
#include <math.h>

#define SRATE   24000.0
#define NB      8
#define NT      48000
#define NH      60
#define NC      100
#define NFMT    5
#define CTS     64
#define NCH     (NT / CTS)       // 750 chunks per batch (= waves per batch)
#define TWO_PI  6.283185307179586476925286766559
#define PSC     (1.0f / 1024.0f) // exact 2^-10 prescale
#define NYQS    11.71875f        // 12000 * 2^-10

typedef float v2f __attribute__((ext_vector_type(2)));

// ---------------- kernel 1: per-chunk f0 sums (double) ----------------
__global__ __launch_bounds__(256) void k_partial(const float* __restrict__ f0,
                                                 double* __restrict__ part) {
    int b = blockIdx.y;
    int ch = blockIdx.x * 4 + (threadIdx.x >> 6);
    int lane = threadIdx.x & 63;
    if (ch < NCH) {
        int t = ch * CTS + lane;
        double q = (double)f0[b * NT + t];
        #pragma unroll
        for (int off = 32; off > 0; off >>= 1)
            q += __shfl_down(q, off, 64);
        if (lane == 0) part[b * NCH + ch] = q;
    }
}

// ---------------- kernel 2: main synthesis ----------------
// R15 base (LDS coef bank, 4 waves/block) + nyquist line-skip on amp loads:
// line i=2 (harmonics 4j+33..36) dead iff f0*(4j+33) >= 12000 (P~12%),
// line i=3 (4j+49..52) dead iff f0*(4j+49) >= 12000 (P~39%). Dead loads are
// zero-filled; the fm mask already zeroes those pairs, so the predicate is
// correctness-neutral and saves ~10% of amp HBM traffic.
__global__ __launch_bounds__(256) void k_main(const float* __restrict__ f0,
                                              const float* __restrict__ amps,
                                              const float* __restrict__ ffq,
                                              const float* __restrict__ fbw,
                                              const float* __restrict__ fam,
                                              const float* __restrict__ initp,
                                              const double* __restrict__ part,
                                              float* __restrict__ out) {
    int b = blockIdx.y;
    int wv = threadIdx.x >> 6;
    int ch = blockIdx.x * 4 + wv;
    int lane = threadIdx.x & 63;
    if (ch >= NCH) return;
    int t0 = ch * CTS;
    int g0 = lane >> 2, j = lane & 3;
    const float4 f4z = make_float4(0.f, 0.f, 0.f, 0.f);
    const float* ab = amps + (size_t)b * NT * NH;

    __shared__ float coef[4][17][64];   // per-wave coefficient bank

    // always-live lines (harmonics 1..32) of passes p: issue immediately
    #define AMPLD01(S0, S1, p)                                                \
        { const float4* rr =                                                  \
              (const float4*)(ab + (size_t)(t0 + (p) * 16 + g0) * NH);        \
          S0 = rr[j]; S1 = rr[4 + j]; }
    // conditionally-live lines (harmonics 33..60), predicated on f0 at the
    // group timestep of pass p
    #define AMPLD23(S2, S3, p, f0g)                                           \
        { const float4* rr =                                                  \
              (const float4*)(ab + (size_t)(t0 + (p) * 16 + g0) * NH);        \
          S2 = ((f0g) * (float)(4 * j + 33) < 12000.0f) ? rr[8 + j] : f4z;    \
          S3 = (j < 3 && (f0g) * (float)(4 * j + 49) < 12000.0f)              \
                   ? rr[12 + j] : f4z; }

    // ---- q0/q1 of passes 0,1 at cycle 0 ----
    float4 A0, A1, A2, A3, B0, B1, B2, B3;
    AMPLD01(A0, A1, 0)
    AMPLD01(B0, B1, 1)

    // ---- group-timestep f0 values for the 4 passes (64B line per wave) ----
    const float* f0row = f0 + b * NT + t0;
    float f0gA = f0row[g0];
    float f0gB = f0row[16 + g0];
    float f0gC = f0row[32 + g0];
    float f0gD = f0row[48 + g0];

    // ---- preamble loads ----
    const double* pb = part + b * NCH;
    double pv[12];
    #pragma unroll
    for (int k = 0; k < 12; ++k) {
        int idx = k * 64 + lane;
        pv[k] = (idx < NCH) ? pb[idx] : 0.0;
    }
    float f0v = f0row[lane];

    double srcd = (double)(t0 + lane) * (99.0 / 47999.0);
    int i0 = (int)srcd;
    if (i0 > NC - 2) i0 = NC - 2;
    float frac = (float)(srcd - (double)i0);
    float omf = 1.0f - frac;
    const float* Fq = ffq + (b * NC + i0) * NFMT;
    const float* Bw = fbw + (b * NC + i0) * NFMT;
    const float* Am = fam + (b * NC + i0) * NFMT;

    // ---- predicated lines for passes 0,1 (after f0gA/B arrive) ----
    AMPLD23(A2, A3, 0, f0gA)
    AMPLD23(B2, B3, 1, f0gB)

    // ---- preamble compute (amp loads in flight) ----
    double sl = 0.0, sa = 0.0;
    #pragma unroll
    for (int k = 0; k < 12; ++k) {
        int idx = k * 64 + lane;
        sa += pv[k];
        if (idx < ch) sl += pv[k];
    }
    #pragma unroll
    for (int off = 1; off < 64; off <<= 1) {
        sl += __shfl_xor(sl, off, 64);
        sa += __shfl_xor(sa, off, 64);
    }

    double initrev = (double)initp[b] * (1.0 / TWO_PI);
    if (ch == 0 && lane == 0) {          // designated wave: final phase
        double rv = sa * (1.0 / SRATE) + initrev;
        out[NB * NT + b] = (float)((rv - floor(rv)) * TWO_PI);
    }

    // chunk-uniform fractional prefix (f64 once), then f32 in-chunk scan
    double pfrac = sl * (1.0 / SRATE) + initrev;
    float prefF = (float)(pfrac - floor(pfrac));     // [0,1), wave-uniform

    float incf = f0v;
    #pragma unroll
    for (int off = 1; off < 64; off <<= 1) {
        float n = __shfl_up(incf, off, 64);
        if (lane >= off) incf += n;
    }
    coef[wv][0][lane] = f0v * PSC;
    coef[wv][1][lane] =
        __builtin_amdgcn_fractf(prefF + incf * (1.0f / 24000.0f));

    // formant lerp (lane = ts) -> LDS
    #pragma unroll
    for (int f = 0; f < NFMT; ++f) {
        float fqv = Fq[f] * omf + Fq[NFMT + f] * frac;
        float bwv = Bw[f] * omf + Bw[NFMT + f] * frac;
        float amv = Am[f] * omf + Am[NFMT + f] * frac;
        float bws = bwv * PSC;
        float c2v = bws * bws;
        coef[wv][2 + f][lane]  = fqv * PSC;
        coef[wv][7 + f][lane]  = amv * c2v;
        coef[wv][12 + f][lane] = c2v;
    }
    // same-wave LDS write->read: ordered by lgkmcnt, no barrier needed

    // ---- one pass = 16 ts x 4 lanes; lane j: quads {4j+1..4} +0/16/32/48 ----
    auto do_pass = [&](int p, float4 q0, float4 q1, float4 q2, float4 q3) {
        int gp = (p << 4) + g0;
        float f0s   = coef[wv][0][gp];
        float rev_g = coef[wv][1][gp];
        float hb = (float)(j << 2);
        auto sd = [&](float k) {
            return __builtin_amdgcn_sinf(
                __builtin_amdgcn_fractf((hb + k) * rev_g));
        };
        v2f s01 = {sd(1.0f),  sd(2.0f)};
        v2f s23 = {sd(3.0f),  sd(4.0f)};
        v2f s45 = {sd(17.0f), sd(18.0f)};
        v2f s67 = {sd(19.0f), sd(20.0f)};
        float c16 = __builtin_amdgcn_cosf(
            __builtin_amdgcn_fractf(16.0f * rev_g));    // cos(16*theta)
        v2f cv = {2.0f * c16, 2.0f * c16};
        v2f s89 = cv * s45 - s01;                       // (hb+33,34)
        v2f sAB = cv * s67 - s23;                       // (hb+35,36)
        v2f sCD = cv * s89 - s45;                       // (hb+49,50)
        v2f sEF = cv * sAB - s67;                       // (hb+51,52)
        v2f acc2 = {0.0f, 0.0f};
        auto pairf = [&](float h1, v2f sn, float a0, float a1) {
            v2f hfl = {h1, h1 + 1.0f};
            v2f hs = f0s * hfl;                         // f0*h * 2^-10
            v2f pN = {1.0f, 1.0f}, pD = {1.0f, 1.0f};
            #pragma unroll
            for (int f = 0; f < NFMT; ++f) {
                v2f d = hs - coef[wv][2 + f][gp];
                v2f e = d * d + coef[wv][12 + f][gp];
                pN *= e + coef[wv][7 + f][gp];
                pD *= e;
            }
            float R = __builtin_amdgcn_rcpf(pD.x * pD.y);
            v2f fac = {pN.x * pD.y * R, pN.y * pD.x * R};
            v2f fm;
            fm.x = (hs.x < NYQS) ? fac.x : 0.0f;        // nyquist mask
            fm.y = (hs.y < NYQS) ? fac.y : 0.0f;
            v2f aa = {a0, a1};
            acc2 += (sn * aa) * fm;
        };
        pairf(hb + 1.0f,  s01, q0.x, q0.y);
        pairf(hb + 3.0f,  s23, q0.z, q0.w);
        pairf(hb + 17.0f, s45, q1.x, q1.y);
        pairf(hb + 19.0f, s67, q1.z, q1.w);
        pairf(hb + 33.0f, s89, q2.x, q2.y);
        pairf(hb + 35.0f, sAB, q2.z, q2.w);
        pairf(hb + 49.0f, sCD, q3.x, q3.y);
        pairf(hb + 51.0f, sEF, q3.z, q3.w);
        float acc = acc2.x + acc2.y;
        acc += __shfl_xor(acc, 1, 64);
        acc += __shfl_xor(acc, 2, 64);
        if (j == 0) {
            if (!(f0s > 0.0f)) acc = 0.0f;              // voiced mask
            out[b * NT + t0 + (p << 4) + g0] = acc;
        }
    };

    // ---- 4 passes, double-buffered prefetch (predicated lines throughout) --
    do_pass(0, A0, A1, A2, A3);
    AMPLD01(A0, A1, 2)
    AMPLD23(A2, A3, 2, f0gC)
    do_pass(1, B0, B1, B2, B3);
    AMPLD01(B0, B1, 3)
    AMPLD23(B2, B3, 3, f0gD)
    do_pass(2, A0, A1, A2, A3);
    do_pass(3, B0, B1, B2, B3);
    #undef AMPLD01
    #undef AMPLD23
}

extern "C" void kernel_launch(void* const* d_in, const int* in_sizes, int n_in,
                              void* d_out, int out_size, void* d_ws, size_t ws_size,
                              hipStream_t stream) {
    const float* f0    = (const float*)d_in[0];
    const float* amps  = (const float*)d_in[1];
    const float* ffq   = (const float*)d_in[2];
    const float* fbw   = (const float*)d_in[3];
    const float* fam   = (const float*)d_in[4];
    const float* initp = (const float*)d_in[5];
    float* out = (float*)d_out;

    double* part = (double*)d_ws;                    // NB*NCH doubles (48 KB)

    dim3 gchunk((NCH + 3) / 4, NB);
    k_partial<<<gchunk, 256, 0, stream>>>(f0, part);
    k_main<<<gchunk, 256, 0, stream>>>(f0, amps, ffq, fbw, fam, initp, part, out);
}